// Round 5
// baseline (197.963 us; speedup 1.0000x reference)
//
#include <hip/hip_runtime.h>
#include <hip/hip_bf16.h>
#include <math.h>

#define N_NODES 50000
#define N_EDGES 800000
#define F_DIM 128
#define H_DIM 64
#define IN_DIM 129   // F_DIM + 1 (binary feature)
#define ETOT (N_EDGES + N_NODES)          // 850000 CSR entries
#define PROJ_BLKS ((N_NODES + 31) / 32)   // 1563 (32 nodes/block)
#define OUT_BLKS  ((N_NODES + 31) / 32)   // 1563
#define NB 196                            // node buckets (256 nodes each; last has 80)
#define CAP 6144                          // bucket capacity (mean 4096, sigma 64)
#define EPB2 782                          // edges per bucket-block (256 thr)
#define BKT_BLKS 1024                     // ceil(800000/782)

typedef __hip_bfloat16 bf16;
typedef __attribute__((ext_vector_type(8))) short bf16x8;   // MFMA A/B frag (4 VGPR)
typedef __attribute__((ext_vector_type(4))) float f32x4;    // MFMA C/D frag

static __device__ __forceinline__ float bs2f(short s) {
    union { float f; unsigned u; } c; c.u = ((unsigned)(unsigned short)s) << 16; return c.f;
}
static __device__ __forceinline__ short f2bs(float f) {
    union { bf16 b; short s; } u; u.b = __float2bfloat16(f); return u.s;
}

// ---------------------------------------------------------------------------
// Prep: pack W (proj) and Wo (out) hi/lo MFMA B-fragments once, zero gcur.
//   proj: fid = wave*8 + nt*4 + ks (32 frags), slot = fid*64 + lane, 8 bf16/slot
//   out:  fid = wave*4 + nt*2 + ks (16 frags), same slot scheme
// ---------------------------------------------------------------------------
__global__ __launch_bounds__(256) void prep_kernel(
    const float* __restrict__ Wl, const float* __restrict__ Wr,
    const float* __restrict__ Wo,
    bf16* __restrict__ whi, bf16* __restrict__ wlo,
    bf16* __restrict__ wohi, bf16* __restrict__ wolo,
    int* __restrict__ gcur)
{
    int b = blockIdx.x, t = threadIdx.x;
    if (b < 8) {                              // [Wl;Wr] frags: 2048 slots
        int s = b * 256 + t;
        int fid = s >> 6, l = s & 63;
        int wave = fid >> 3, nt = (fid >> 2) & 1, ks = fid & 3;
        int ch = wave * 32 + nt * 16 + (l & 15);
        int kb = ks * 32 + (l >> 4) * 8;
        const float* wrow = (ch < 64) ? Wl + (size_t)ch * IN_DIM
                                      : Wr + (size_t)(ch - 64) * IN_DIM;
        #pragma unroll
        for (int j = 0; j < 8; ++j) {
            float v = wrow[kb + j];
            short hs = f2bs(v);
            short ls = f2bs(v - bs2f(hs));
            ((short*)whi)[(size_t)s * 8 + j] = hs;
            ((short*)wlo)[(size_t)s * 8 + j] = ls;
        }
    } else if (b < 12) {                      // Wo frags: 1024 slots
        int s = (b - 8) * 256 + t;
        int fid = s >> 6, l = s & 63;
        int wave = fid >> 2, nt = (fid >> 1) & 1, ks = fid & 1;
        int ch = wave * 32 + nt * 16 + (l & 15);
        int kb = ks * 32 + (l >> 4) * 8;
        const float* wrow = Wo + (size_t)ch * H_DIM;
        #pragma unroll
        for (int j = 0; j < 8; ++j) {
            float v = wrow[kb + j];
            short hs = f2bs(v);
            short ls = f2bs(v - bs2f(hs));
            ((short*)wohi)[(size_t)s * 8 + j] = hs;
            ((short*)wolo)[(size_t)s * 8 + j] = ls;
        }
    } else {                                  // zero bucket cursors
        if (t < NB) gcur[t] = 0;
    }
}

// ---------------------------------------------------------------------------
// H1 (hybrid dispatch — overlap two independent jobs on the same CUs):
//  blocks [0, PROJ_BLKS):          proj: [xl|xr] = x @ [Wl;Wr]^T + bias (MFMA)
//  blocks [PROJ_BLKS, +BKT_BLKS):  bucket sort level 1: 782 edges/block staged
//    in LDS packed (dst<<16|src), 196-bin LDS histogram, ONE returning global
//    atomic per (block,bucket) reserves a range (~200k total, hidden under
//    proj's MFMA occupancy), scatter to bucket storage.
// Both paths: 8 KB LDS, 256 thr, ~64 VGPR -> 8 blocks/CU co-resident.
// ---------------------------------------------------------------------------
__global__ __launch_bounds__(256) void h1_kernel(
    const float* __restrict__ xf, const float* __restrict__ xb,
    const float* __restrict__ Wl, const float* __restrict__ bl,
    const float* __restrict__ Wr, const float* __restrict__ br,
    const bf16* __restrict__ whi, const bf16* __restrict__ wlo,
    const int* __restrict__ esrc, const int* __restrict__ edst,
    bf16* __restrict__ xl, bf16* __restrict__ xr,
    int* __restrict__ gcur, unsigned* __restrict__ bstore)
{
    __shared__ int smem[2048];   // 8 KB, aliased per path

    if (blockIdx.x >= PROJ_BLKS) {
        // ---- bucket path ----
        unsigned* ent = (unsigned*)smem;        // 782
        int* hist  = smem + 782;                // 196
        int* lbase = smem + 978;                // 196
        int* c2    = smem + 1174;               // 196
        int t = threadIdx.x;
        if (t < NB) hist[t] = 0;
        __syncthreads();

        int e0 = (blockIdx.x - PROJ_BLKS) * EPB2;
        int cnt = N_EDGES - e0; if (cnt > EPB2) cnt = EPB2;
        for (int k = t; k < cnt; k += 256) {
            int dst = edst[e0 + k];
            ent[k] = ((unsigned)dst << 16) | (unsigned)esrc[e0 + k];
            atomicAdd(&hist[dst >> 8], 1);      // LDS atomic
        }
        __syncthreads();

        if (t < NB) {
            int hh = hist[t];
            lbase[t] = hh ? atomicAdd(&gcur[t], hh) : 0;   // range reservation
            c2[t] = 0;
        }
        __syncthreads();

        for (int k = t; k < cnt; k += 256) {
            unsigned en = ent[k];
            int j = en >> 24;                   // dst>>8
            int r = atomicAdd(&c2[j], 1);       // LDS atomic
            bstore[(size_t)j * CAP + lbase[j] + r] = en;
        }
        return;
    }

    // ---- proj path ----
    short* lds = (short*)smem;   // [node_local][ch], 16B chunks XOR-swizzled

    int wave = threadIdx.x >> 6;
    int lane = threadIdx.x & 63;
    int n = lane & 15, q = lane >> 4;
    int node0 = blockIdx.x * 32;

    bf16x8 bhi[2][4], blo_[2][4];
    float biasv[2], w128[2];
    #pragma unroll
    for (int nt = 0; nt < 2; ++nt) {
        int ch = wave * 32 + nt * 16 + n;
        #pragma unroll
        for (int ks = 0; ks < 4; ++ks) {
            int fid = wave * 8 + nt * 4 + ks;
            bhi[nt][ks]  = *(const bf16x8*)(whi + ((size_t)fid * 64 + lane) * 8);
            blo_[nt][ks] = *(const bf16x8*)(wlo + ((size_t)fid * 64 + lane) * 8);
        }
        biasv[nt] = (ch < 64) ? bl[ch] : br[ch - 64];
        w128[nt]  = (ch < 64) ? Wl[(size_t)ch * IN_DIM + 128]
                              : Wr[(size_t)(ch - 64) * IN_DIM + 128];
    }

    #pragma unroll
    for (int mt = 0; mt < 2; ++mt) {
        int nb = node0 + mt * 16;
        if (nb < N_NODES) {   // N_NODES % 16 == 0: tile fully valid or skipped
            const float* xrow = xf + (size_t)(nb + n) * F_DIM;
            bf16x8 a[4];
            #pragma unroll
            for (int ks = 0; ks < 4; ++ks) {
                float4 u = *(const float4*)(xrow + ks * 32 + q * 8);
                float4 v = *(const float4*)(xrow + ks * 32 + q * 8 + 4);
                bf16x8 tt;
                tt[0] = f2bs(u.x); tt[1] = f2bs(u.y); tt[2] = f2bs(u.z); tt[3] = f2bs(u.w);
                tt[4] = f2bs(v.x); tt[5] = f2bs(v.y); tt[6] = f2bs(v.z); tt[7] = f2bs(v.w);
                a[ks] = tt;
            }
            f32x4 acc[2] = {{0.f,0.f,0.f,0.f},{0.f,0.f,0.f,0.f}};
            #pragma unroll
            for (int ks = 0; ks < 4; ++ks) {
                #pragma unroll
                for (int nt = 0; nt < 2; ++nt) {
                    acc[nt] = __builtin_amdgcn_mfma_f32_16x16x32_bf16(a[ks], bhi[nt][ks],  acc[nt], 0, 0, 0);
                    acc[nt] = __builtin_amdgcn_mfma_f32_16x16x32_bf16(a[ks], blo_[nt][ks], acc[nt], 0, 0, 0);
                }
            }
            float4 xbv = *(const float4*)(xb + nb + q * 4);
            float xbr[4] = {xbv.x, xbv.y, xbv.z, xbv.w};
            #pragma unroll
            for (int nt = 0; nt < 2; ++nt) {
                int ch = wave * 32 + nt * 16 + n;
                int blk = ch >> 3, pos = ch & 7;
                #pragma unroll
                for (int r = 0; r < 4; ++r) {
                    int nodeL = mt * 16 + q * 4 + r;   // C/D: row = quad*4 + reg
                    float val = acc[nt][r] + xbr[r] * w128[nt] + biasv[nt];
                    lds[nodeL * 128 + ((blk ^ (nodeL & 7)) << 3) + pos] = f2bs(val);
                }
            }
        }
    }
    __syncthreads();

    // Coalesced write-back: thread t -> node t>>3, 16B chunk t&7 of xl and xr.
    int nl = threadIdx.x >> 3, bk = threadIdx.x & 7;
    int node = node0 + nl;
    if (node < N_NODES) {
        bf16x8 v0 = *(const bf16x8*)(lds + nl * 128 + ((bk ^ (nl & 7)) << 3));
        *(bf16x8*)(xl + (size_t)node * H_DIM + bk * 8) = v0;
        bf16x8 v1 = *(const bf16x8*)(lds + nl * 128 + (((8 + bk) ^ (nl & 7)) << 3));
        *(bf16x8*)(xr + (size_t)node * H_DIM + bk * 8) = v1;
    }
}

// ---------------------------------------------------------------------------
// K-csr: level 2, 512 thr/block (784->1568 waves: better SIMD fill).
// One block per bucket: load entries to LDS, 256-bin LDS histogram by
// dst&255, LDS scans -> offs[] (self-loop at segment head) and final CSR.
// ---------------------------------------------------------------------------
__global__ __launch_bounds__(512) void csr_kernel(
    const int* __restrict__ gcur, const unsigned* __restrict__ bstore,
    int* __restrict__ offs, int* __restrict__ csr_src)
{
    __shared__ unsigned ent[CAP];
    __shared__ int sh[256], h256[256], start[256], c2[256];
    __shared__ int bb_s, C_s;
    int j = blockIdx.x, t = threadIdx.x;

    // bucket-base prefix: val_j' = gcur[j'] + (real nodes in bucket j')
    int val = 0;
    if (t < NB) val = gcur[t] + ((t < NB - 1) ? 256 : (N_NODES - (NB - 1) * 256));
    if (t < 256) sh[t] = val;
    __syncthreads();
    #pragma unroll
    for (int d = 1; d < 256; d <<= 1) {
        int x = (t >= d && t < 256) ? sh[t - d] : 0;
        __syncthreads();
        if (t < 256) sh[t] += x;
        __syncthreads();
    }
    if (t == j) bb_s = sh[t] - val;        // exclusive prefix at own bucket
    if (t == 0) C_s = gcur[j];
    if (t < 256) h256[t] = 0;
    __syncthreads();
    int bb = bb_s, C = C_s;

    for (int k = t; k < C; k += 512) {
        unsigned en = bstore[(size_t)j * CAP + k];
        ent[k] = en;
        atomicAdd(&h256[(en >> 16) & 255], 1);   // LDS atomic
    }
    __syncthreads();

    // scan of per-node widths (deg + 1 self-loop for real nodes)
    int w = 0;
    if (t < 256) {
        w = h256[t] + ((j * 256 + t < N_NODES) ? 1 : 0);
        sh[t] = w;
    }
    __syncthreads();
    #pragma unroll
    for (int d = 1; d < 256; d <<= 1) {
        int x = (t >= d && t < 256) ? sh[t - d] : 0;
        __syncthreads();
        if (t < 256) sh[t] += x;
        __syncthreads();
    }
    if (t < 256) {
        int st = bb + sh[t] - w;
        start[t] = st;
        c2[t] = 0;
        int node = j * 256 + t;
        if (node < N_NODES) {
            offs[node] = st;
            csr_src[st] = node;             // self-loop at segment head
        }
    }
    if (j == NB - 1 && t == 0) offs[N_NODES] = ETOT;   // sentinel
    __syncthreads();

    for (int k = t; k < C; k += 512) {
        unsigned en = ent[k];
        int bin = (en >> 16) & 255;
        int r = atomicAdd(&c2[bin], 1);     // LDS atomic
        csr_src[start[bin] + 1 + r] = (int)(en & 0xffffu);
    }
}

// ---------------------------------------------------------------------------
// K2b (fused score + aggregate, wave-per-dst, depth-3 pipeline).
// ---------------------------------------------------------------------------
__global__ __launch_bounds__(256) void agg_fused(
    const int* __restrict__ csr_src, const int* __restrict__ offs,
    const bf16* __restrict__ xl, const bf16* __restrict__ xr,
    const float* __restrict__ att, const float* __restrict__ gb,
    bf16* __restrict__ h)
{
    int wid  = (blockIdx.x * 256 + threadIdx.x) >> 6;   // dst node
    int lane = threadIdx.x & 63;
    if (wid >= N_NODES) return;
    int g  = lane >> 3;   // edge slot within batch
    int c8 = lane & 7;    // channel octet

    float attv[8], xrv[8];
    {
        bf16x8 xrow = *(const bf16x8*)(xr + (size_t)wid * H_DIM + c8 * 8);
        float4 a0 = *(const float4*)(att + c8 * 8);
        float4 a1 = *(const float4*)(att + c8 * 8 + 4);
        attv[0] = a0.x; attv[1] = a0.y; attv[2] = a0.z; attv[3] = a0.w;
        attv[4] = a1.x; attv[5] = a1.y; attv[6] = a1.z; attv[7] = a1.w;
        #pragma unroll
        for (int j = 0; j < 8; ++j) xrv[j] = bs2f(xrow[j]);
    }

    int beg = offs[wid];
    int end = offs[wid + 1];          // >= beg+1 (self-loop)
    int last = end - 1;
    float den = 0.f;
    float acc[8] = {0.f, 0.f, 0.f, 0.f, 0.f, 0.f, 0.f, 0.f};

    int i0 = beg + g;        i0 = (i0 < end) ? i0 : last;
    int i1 = beg + 8 + g;    i1 = (i1 < end) ? i1 : last;
    int i2 = beg + 16 + g;   i2 = (i2 < end) ? i2 : last;
    int srcC = csr_src[i2];                                    // idx batch+2
    bf16x8 xa = *(const bf16x8*)(xl + (size_t)csr_src[i0] * H_DIM + c8 * 8);
    bf16x8 xb = *(const bf16x8*)(xl + (size_t)csr_src[i1] * H_DIM + c8 * 8);

    for (int base = beg; base < end; base += 8) {
        int i3 = base + 24 + g;  i3 = (i3 < end) ? i3 : last;
        int srcD = csr_src[i3];                                // idx batch+3
        bf16x8 xc = *(const bf16x8*)(xl + (size_t)srcC * H_DIM + c8 * 8);

        bool valid = (base + g) < end;
        float xv[8], p = 0.f;
        #pragma unroll
        for (int j = 0; j < 8; ++j) {
            xv[j] = bs2f(xa[j]);
            float m = xv[j] + xrv[j];
            m = (m > 0.f) ? m : 0.2f * m;
            p += m * attv[j];
        }
        p += __shfl_xor(p, 1);
        p += __shfl_xor(p, 2);
        p += __shfl_xor(p, 4);      // all lanes of group g now hold p_g
        float ex = valid ? __expf(p) : 0.f;
        den += ex;
        #pragma unroll
        for (int j = 0; j < 8; ++j) acc[j] += ex * xv[j];

        xa = xb;
        xb = xc;
        srcC = srcD;
    }

    // combine the 8 edge-groups (once per dst)
    #pragma unroll
    for (int j = 0; j < 8; ++j) {
        acc[j] += __shfl_xor(acc[j], 8);
        acc[j] += __shfl_xor(acc[j], 16);
        acc[j] += __shfl_xor(acc[j], 32);
    }
    den += __shfl_xor(den, 8);
    den += __shfl_xor(den, 16);
    den += __shfl_xor(den, 32);

    if (g == 0) {
        float inv = 1.0f / den;
        float4 g0 = *(const float4*)(gb + c8 * 8);
        float4 g1 = *(const float4*)(gb + c8 * 8 + 4);
        float gbv[8] = {g0.x, g0.y, g0.z, g0.w, g1.x, g1.y, g1.z, g1.w};
        bf16x8 ov;
        #pragma unroll
        for (int j = 0; j < 8; ++j) {
            float v = acc[j] * inv + gbv[j];
            v = (v > 0.f) ? v : expm1f(v);
            ov[j] = f2bs(v);
        }
        *(bf16x8*)(h + (size_t)wid * H_DIM + c8 * 8) = ov;
    }
}

// ---------------------------------------------------------------------------
// K3 (MFMA): logits = h @ Wo^T + bo (+ softplus(dispersion) tail on block 0).
// 32 nodes/block; B-frags from the prep pack; epilogue staged through a
// padded-row LDS tile (32 x 132 f32) -> per-wave-contiguous float4 stores.
// ---------------------------------------------------------------------------
__global__ __launch_bounds__(256) void out_mfma(
    const bf16* __restrict__ h,
    const bf16* __restrict__ wohi, const bf16* __restrict__ wolo,
    const float* __restrict__ bo, const float* __restrict__ disp,
    float* __restrict__ out)
{
    if (blockIdx.x == 0 && threadIdx.x < F_DIM) {
        float d = disp[threadIdx.x];
        out[(size_t)N_NODES * F_DIM + threadIdx.x] = (d > 20.f) ? d : log1pf(__expf(d));
    }

    __shared__ float ldso[32 * 132];   // +4 f32 row pad -> bank spread

    int wave = threadIdx.x >> 6;
    int lane = threadIdx.x & 63;
    int n = lane & 15, q = lane >> 4;
    int node0 = blockIdx.x * 32;

    bf16x8 bhi[2][2], blo_[2][2];
    float bov[2];
    #pragma unroll
    for (int nt = 0; nt < 2; ++nt) {
        int ch = wave * 32 + nt * 16 + n;
        #pragma unroll
        for (int ks = 0; ks < 2; ++ks) {
            int fid = wave * 4 + nt * 2 + ks;
            bhi[nt][ks]  = *(const bf16x8*)(wohi + ((size_t)fid * 64 + lane) * 8);
            blo_[nt][ks] = *(const bf16x8*)(wolo + ((size_t)fid * 64 + lane) * 8);
        }
        bov[nt] = bo[ch];
    }

    #pragma unroll
    for (int mt = 0; mt < 2; ++mt) {
        int nb = node0 + mt * 16;
        if (nb < N_NODES) {   // uniform per block
            const bf16* hrow = h + (size_t)(nb + n) * H_DIM;
            bf16x8 a[2];
            #pragma unroll
            for (int ks = 0; ks < 2; ++ks)
                a[ks] = *(const bf16x8*)(hrow + ks * 32 + q * 8);
            f32x4 acc[2] = {{0.f,0.f,0.f,0.f},{0.f,0.f,0.f,0.f}};
            #pragma unroll
            for (int ks = 0; ks < 2; ++ks) {
                #pragma unroll
                for (int nt = 0; nt < 2; ++nt) {
                    acc[nt] = __builtin_amdgcn_mfma_f32_16x16x32_bf16(a[ks], bhi[nt][ks],  acc[nt], 0, 0, 0);
                    acc[nt] = __builtin_amdgcn_mfma_f32_16x16x32_bf16(a[ks], blo_[nt][ks], acc[nt], 0, 0, 0);
                }
            }
            #pragma unroll
            for (int nt = 0; nt < 2; ++nt) {
                int ch = wave * 32 + nt * 16 + n;
                #pragma unroll
                for (int r = 0; r < 4; ++r) {
                    int nodeL = mt * 16 + q * 4 + r;
                    ldso[nodeL * 132 + ch] = acc[nt][r] + bov[nt];
                }
            }
        }
    }
    __syncthreads();

    // Coalesced write-back: thread t -> node t>>3, 64B chunk t&7.
    int nl = threadIdx.x >> 3, c = threadIdx.x & 7;
    int node = node0 + nl;
    if (node < N_NODES) {
        const float* srcp = ldso + nl * 132 + c * 16;
        float* dstp = out + (size_t)node * F_DIM + c * 16;
        #pragma unroll
        for (int i = 0; i < 4; ++i)
            *(float4*)(dstp + i * 4) = *(const float4*)(srcp + i * 4);
    }
}

// ---------------------------------------------------------------------------
extern "C" void kernel_launch(void* const* d_in, const int* in_sizes, int n_in,
                              void* d_out, int out_size, void* d_ws, size_t ws_size,
                              hipStream_t stream)
{
    const float* xf  = (const float*)d_in[0];
    const float* xb  = (const float*)d_in[1];
    const int*   ei  = (const int*)d_in[2];    // [2, E] int32, row-major
    const float* Wl  = (const float*)d_in[3];
    const float* bl  = (const float*)d_in[4];
    const float* Wr  = (const float*)d_in[5];
    const float* br  = (const float*)d_in[6];
    const float* att = (const float*)d_in[7];
    const float* gb  = (const float*)d_in[8];
    const float* Wo  = (const float*)d_in[9];
    const float* bo  = (const float*)d_in[10];
    const float* dp  = (const float*)d_in[11];
    float* out = (float*)d_out;
    const int* esrc = ei;
    const int* edst = ei + N_EDGES;

    // ws layout (16B-aligned segments):
    //  xl bf16[N*64] | xr bf16[N*64] | h bf16[N*64] (bstore overlays h:
    //  disjoint lifetimes — bstore written by h1's bucket half, read by csr,
    //  both before agg writes h) | csr_src int[ETOT] | offs int[N+1] |
    //  gcur int[NB] | whi | wlo | wohi | wolo
    char* ws = (char*)d_ws;
    const size_t SZB = (size_t)N_NODES * H_DIM * sizeof(bf16);   // 6.4 MB
    bf16*  xl      = (bf16*)(ws);
    bf16*  xr      = (bf16*)(ws + SZB);
    bf16*  h       = (bf16*)(ws + 2 * SZB);
    unsigned* bstore = (unsigned*)h;          // overlay (4.8 MB <= 6.4 MB)
    int*   csr_src = (int*)(ws + 3 * SZB);
    int*   offs    = (int*)(ws + 3 * SZB + (size_t)ETOT * 4);
    int*   gcur    = offs + (N_NODES + 4);
    bf16*  whi     = (bf16*)(gcur + NB + 12);
    bf16*  wlo     = whi + 16384;
    bf16*  wohi    = wlo + 16384;
    bf16*  wolo    = wohi + 8192;

    prep_kernel<<<13, 256, 0, stream>>>(Wl, Wr, Wo, whi, wlo, wohi, wolo, gcur);

    h1_kernel<<<PROJ_BLKS + BKT_BLKS, 256, 0, stream>>>(
        xf, xb, Wl, bl, Wr, br, whi, wlo, esrc, edst, xl, xr, gcur, bstore);

    csr_kernel<<<NB, 512, 0, stream>>>(gcur, bstore, offs, csr_src);

    agg_fused<<<(N_NODES * 64) / 256, 256, 0, stream>>>(csr_src, offs,
                                                        xl, xr, att, gb, h);

    out_mfma<<<OUT_BLKS, 256, 0, stream>>>(h, wohi, wolo, bo, dp, out);
}

// Round 6
// 185.992 us; speedup vs baseline: 1.0644x; 1.0644x over previous
//
#include <hip/hip_runtime.h>
#include <hip/hip_bf16.h>
#include <math.h>

#define N_NODES 50000
#define N_EDGES 800000
#define F_DIM 128
#define H_DIM 64
#define IN_DIM 129   // F_DIM + 1 (binary feature)
#define ETOT (N_EDGES + N_NODES)          // 850000 CSR entries
#define PROJ_BLKS ((N_NODES + 31) / 32)   // 1563 (32 nodes/block)
#define OUT_BLKS  ((N_NODES + 31) / 32)   // 1563
#define NB 196                            // node buckets (256 nodes each; last has 80)
#define CAP 6144                          // csr LDS capacity (mean 4096, sigma 64)
#define EPB 3125                          // edges per bucket block (256 blocks exact)
#define BKT_BLKS 256

typedef __hip_bfloat16 bf16;
typedef __attribute__((ext_vector_type(8))) short bf16x8;   // MFMA A/B frag (4 VGPR)
typedef __attribute__((ext_vector_type(4))) float f32x4;    // MFMA C/D frag

static __device__ __forceinline__ float bs2f(short s) {
    union { float f; unsigned u; } c; c.u = ((unsigned)(unsigned short)s) << 16; return c.f;
}
static __device__ __forceinline__ short f2bs(float f) {
    union { bf16 b; short s; } u; u.b = __float2bfloat16(f); return u.s;
}

// ---------------------------------------------------------------------------
// Prep: pack W (proj) and Wo (out) hi/lo MFMA B-fragments once, zero gtot.
//   proj: fid = wave*8 + nt*4 + ks (32 frags), slot = fid*64 + lane, 8 bf16/slot
//   out:  fid = wave*4 + nt*2 + ks (16 frags), same slot scheme
// ---------------------------------------------------------------------------
__global__ __launch_bounds__(256) void prep_kernel(
    const float* __restrict__ Wl, const float* __restrict__ Wr,
    const float* __restrict__ Wo,
    bf16* __restrict__ whi, bf16* __restrict__ wlo,
    bf16* __restrict__ wohi, bf16* __restrict__ wolo,
    int* __restrict__ gtot)
{
    int b = blockIdx.x, t = threadIdx.x;
    if (b < 8) {                              // [Wl;Wr] frags: 2048 slots
        int s = b * 256 + t;
        int fid = s >> 6, l = s & 63;
        int wave = fid >> 3, nt = (fid >> 2) & 1, ks = fid & 3;
        int ch = wave * 32 + nt * 16 + (l & 15);
        int kb = ks * 32 + (l >> 4) * 8;
        const float* wrow = (ch < 64) ? Wl + (size_t)ch * IN_DIM
                                      : Wr + (size_t)(ch - 64) * IN_DIM;
        #pragma unroll
        for (int j = 0; j < 8; ++j) {
            float v = wrow[kb + j];
            short hs = f2bs(v);
            short ls = f2bs(v - bs2f(hs));
            ((short*)whi)[(size_t)s * 8 + j] = hs;
            ((short*)wlo)[(size_t)s * 8 + j] = ls;
        }
    } else if (b < 12) {                      // Wo frags: 1024 slots
        int s = (b - 8) * 256 + t;
        int fid = s >> 6, l = s & 63;
        int wave = fid >> 2, nt = (fid >> 1) & 1, ks = fid & 1;
        int ch = wave * 32 + nt * 16 + (l & 15);
        int kb = ks * 32 + (l >> 4) * 8;
        const float* wrow = Wo + (size_t)ch * H_DIM;
        #pragma unroll
        for (int j = 0; j < 8; ++j) {
            float v = wrow[kb + j];
            short hs = f2bs(v);
            short ls = f2bs(v - bs2f(hs));
            ((short*)wohi)[(size_t)s * 8 + j] = hs;
            ((short*)wolo)[(size_t)s * 8 + j] = ls;
        }
    } else {                                  // zero bucket totals
        if (t < NB) gtot[t] = 0;
    }
}

// ---------------------------------------------------------------------------
// H1 (hybrid dispatch — overlap two independent jobs on the same CUs):
//  blocks [0, PROJ_BLKS):          proj: [xl|xr] = x @ [Wl;Wr]^T + bias (MFMA)
//  blocks [PROJ_BLKS, +256):       bucket sort level 1, ZERO returning global
//    atomics: 3125 edges register-staged (13/thread), 196-bin LDS histogram +
//    LDS scan -> per-block-private scatter into bstore2[b*3125+..] grouped by
//    bucket; publishes (base,count) in bofsT and non-returning gtot adds.
// Both paths: 8 KB LDS, 256 thr, ~64 VGPR -> 8 blocks/CU co-resident.
// ---------------------------------------------------------------------------
__global__ __launch_bounds__(256) void h1_kernel(
    const float* __restrict__ xf, const float* __restrict__ xb,
    const float* __restrict__ Wl, const float* __restrict__ bl,
    const float* __restrict__ Wr, const float* __restrict__ br,
    const bf16* __restrict__ whi, const bf16* __restrict__ wlo,
    const int* __restrict__ esrc, const int* __restrict__ edst,
    bf16* __restrict__ xl, bf16* __restrict__ xr,
    int* __restrict__ gtot, unsigned* __restrict__ bstore2,
    int* __restrict__ bofsT)
{
    __shared__ int smem[2048];   // 8 KB, aliased per path

    if (blockIdx.x >= PROJ_BLKS) {
        // ---- bucket path (atomic-free placement) ----
        int* hist = smem;           // 196
        int* base = smem + 256;     // 196
        int* cur  = smem + 512;     // 196
        int* shs  = smem + 768;     // 256 scan temp
        int t = threadIdx.x;
        int b = blockIdx.x - PROJ_BLKS;
        int e0 = b * EPB;
        if (t < NB) hist[t] = 0;
        __syncthreads();

        int myd[13]; int mys[13];
        #pragma unroll
        for (int i = 0; i < 13; ++i) {       // 3125 = 12*256 + 53
            int k = t + i * 256;
            bool v = k < EPB;
            int dst = v ? edst[e0 + k] : -1;
            int sc  = v ? esrc[e0 + k] : 0;
            myd[i] = dst; mys[i] = sc;
            if (v) atomicAdd(&hist[dst >> 8], 1);     // LDS atomic
        }
        __syncthreads();

        int hv = (t < NB) ? hist[t] : 0;
        shs[t] = hv;
        __syncthreads();
        #pragma unroll
        for (int d = 1; d < 256; d <<= 1) {
            int x = (t >= d) ? shs[t - d] : 0;
            __syncthreads();
            shs[t] += x;
            __syncthreads();
        }
        if (t < NB) {
            int bs = shs[t] - hv;
            base[t] = bs;
            cur[t] = 0;
            if (hv) atomicAdd(&gtot[t], hv);          // non-returning global
            bofsT[t * 256 + b] = (bs << 16) | hv;     // packed (base,count)
        }
        __syncthreads();

        #pragma unroll
        for (int i = 0; i < 13; ++i) {
            if (myd[i] >= 0) {
                int j = myd[i] >> 8;
                int slot = base[j] + atomicAdd(&cur[j], 1);   // LDS atomic
                bstore2[(size_t)e0 + slot] =
                    ((unsigned)myd[i] << 16) | (unsigned)mys[i];
            }
        }
        return;
    }

    // ---- proj path ----
    short* lds = (short*)smem;   // [node_local][ch], 16B chunks XOR-swizzled

    int wave = threadIdx.x >> 6;
    int lane = threadIdx.x & 63;
    int n = lane & 15, q = lane >> 4;
    int node0 = blockIdx.x * 32;

    bf16x8 bhi[2][4], blo_[2][4];
    float biasv[2], w128[2];
    #pragma unroll
    for (int nt = 0; nt < 2; ++nt) {
        int ch = wave * 32 + nt * 16 + n;
        #pragma unroll
        for (int ks = 0; ks < 4; ++ks) {
            int fid = wave * 8 + nt * 4 + ks;
            bhi[nt][ks]  = *(const bf16x8*)(whi + ((size_t)fid * 64 + lane) * 8);
            blo_[nt][ks] = *(const bf16x8*)(wlo + ((size_t)fid * 64 + lane) * 8);
        }
        biasv[nt] = (ch < 64) ? bl[ch] : br[ch - 64];
        w128[nt]  = (ch < 64) ? Wl[(size_t)ch * IN_DIM + 128]
                              : Wr[(size_t)(ch - 64) * IN_DIM + 128];
    }

    #pragma unroll
    for (int mt = 0; mt < 2; ++mt) {
        int nb = node0 + mt * 16;
        if (nb < N_NODES) {
            const float* xrow = xf + (size_t)(nb + n) * F_DIM;
            bf16x8 a[4];
            #pragma unroll
            for (int ks = 0; ks < 4; ++ks) {
                float4 u = *(const float4*)(xrow + ks * 32 + q * 8);
                float4 v = *(const float4*)(xrow + ks * 32 + q * 8 + 4);
                bf16x8 tt;
                tt[0] = f2bs(u.x); tt[1] = f2bs(u.y); tt[2] = f2bs(u.z); tt[3] = f2bs(u.w);
                tt[4] = f2bs(v.x); tt[5] = f2bs(v.y); tt[6] = f2bs(v.z); tt[7] = f2bs(v.w);
                a[ks] = tt;
            }
            f32x4 acc[2] = {{0.f,0.f,0.f,0.f},{0.f,0.f,0.f,0.f}};
            #pragma unroll
            for (int ks = 0; ks < 4; ++ks) {
                #pragma unroll
                for (int nt = 0; nt < 2; ++nt) {
                    acc[nt] = __builtin_amdgcn_mfma_f32_16x16x32_bf16(a[ks], bhi[nt][ks],  acc[nt], 0, 0, 0);
                    acc[nt] = __builtin_amdgcn_mfma_f32_16x16x32_bf16(a[ks], blo_[nt][ks], acc[nt], 0, 0, 0);
                }
            }
            float4 xbv = *(const float4*)(xb + nb + q * 4);
            float xbr[4] = {xbv.x, xbv.y, xbv.z, xbv.w};
            #pragma unroll
            for (int nt = 0; nt < 2; ++nt) {
                int ch = wave * 32 + nt * 16 + n;
                int blk = ch >> 3, pos = ch & 7;
                #pragma unroll
                for (int r = 0; r < 4; ++r) {
                    int nodeL = mt * 16 + q * 4 + r;   // C/D: row = quad*4 + reg
                    float val = acc[nt][r] + xbr[r] * w128[nt] + biasv[nt];
                    lds[nodeL * 128 + ((blk ^ (nodeL & 7)) << 3) + pos] = f2bs(val);
                }
            }
        }
    }
    __syncthreads();

    // Coalesced write-back: thread t -> node t>>3, 16B chunk t&7 of xl and xr.
    int nl = threadIdx.x >> 3, bk = threadIdx.x & 7;
    int node = node0 + nl;
    if (node < N_NODES) {
        bf16x8 v0 = *(const bf16x8*)(lds + nl * 128 + ((bk ^ (nl & 7)) << 3));
        *(bf16x8*)(xl + (size_t)node * H_DIM + bk * 8) = v0;
        bf16x8 v1 = *(const bf16x8*)(lds + nl * 128 + (((8 + bk) ^ (nl & 7)) << 3));
        *(bf16x8*)(xr + (size_t)node * H_DIM + bk * 8) = v1;
    }
}

// ---------------------------------------------------------------------------
// K-csr: level 2, 512 thr/block, one block per bucket. Gathers the bucket's
// slices from the 256 per-block regions (coalesced bofsT read + per-thread
// ~16-entry copies), then 256-bin LDS histogram by dst&255, LDS scans ->
// offs[] (self-loop at segment head) and final CSR.
// ---------------------------------------------------------------------------
__global__ __launch_bounds__(512) void csr_kernel(
    const int* __restrict__ gtot, const unsigned* __restrict__ bstore2,
    const int* __restrict__ bofsT,
    int* __restrict__ offs, int* __restrict__ csr_src)
{
    __shared__ unsigned ent[CAP];
    __shared__ int sh[256], gb_[256], bcnt_[256], bbase_[256];
    __shared__ int h256[256], start[256], c2[256];
    __shared__ int bb_s, C_s;
    int j = blockIdx.x, t = threadIdx.x;

    // per-source-block info + scan of counts -> gather bases
    int bcnt = 0;
    if (t < 256) {
        unsigned v = (unsigned)bofsT[j * 256 + t];
        bbase_[t] = (int)(v >> 16);
        bcnt = (int)(v & 0xffffu);
        bcnt_[t] = bcnt;
        sh[t] = bcnt;
    }
    __syncthreads();
    #pragma unroll
    for (int d = 1; d < 256; d <<= 1) {
        int x = (t >= d && t < 256) ? sh[t - d] : 0;
        __syncthreads();
        if (t < 256) sh[t] += x;
        __syncthreads();
    }
    if (t < 256) gb_[t] = sh[t] - bcnt;
    if (t == 255) C_s = sh[255];
    __syncthreads();
    int C = C_s;

    // gather this bucket's entries into LDS
    if (t < 256) {
        const unsigned* p = bstore2 + (size_t)t * EPB + bbase_[t];
        int o = gb_[t];
        int c = bcnt_[t];
        for (int i = 0; i < c; ++i) ent[o + i] = p[i];
    }
    __syncthreads();

    // bucket-base prefix: val_j' = gtot[j'] + (real nodes in bucket j')
    int val = 0;
    if (t < NB) val = gtot[t] + ((t < NB - 1) ? 256 : (N_NODES - (NB - 1) * 256));
    if (t < 256) sh[t] = val;
    __syncthreads();
    #pragma unroll
    for (int d = 1; d < 256; d <<= 1) {
        int x = (t >= d && t < 256) ? sh[t - d] : 0;
        __syncthreads();
        if (t < 256) sh[t] += x;
        __syncthreads();
    }
    if (t == j) bb_s = sh[t] - val;        // exclusive prefix at own bucket
    if (t < 256) h256[t] = 0;
    __syncthreads();
    int bb = bb_s;

    // 256-bin histogram over entries
    for (int k = t; k < C; k += 512)
        atomicAdd(&h256[(ent[k] >> 16) & 255], 1);   // LDS atomic
    __syncthreads();

    // scan of per-node widths (deg + 1 self-loop for real nodes)
    int w = 0;
    if (t < 256) {
        w = h256[t] + ((j * 256 + t < N_NODES) ? 1 : 0);
        sh[t] = w;
    }
    __syncthreads();
    #pragma unroll
    for (int d = 1; d < 256; d <<= 1) {
        int x = (t >= d && t < 256) ? sh[t - d] : 0;
        __syncthreads();
        if (t < 256) sh[t] += x;
        __syncthreads();
    }
    if (t < 256) {
        int st = bb + sh[t] - w;
        start[t] = st;
        c2[t] = 0;
        int node = j * 256 + t;
        if (node < N_NODES) {
            offs[node] = st;
            csr_src[st] = node;             // self-loop at segment head
        }
    }
    if (j == NB - 1 && t == 0) offs[N_NODES] = ETOT;   // sentinel
    __syncthreads();

    for (int k = t; k < C; k += 512) {
        unsigned en = ent[k];
        int bin = (en >> 16) & 255;
        int r = atomicAdd(&c2[bin], 1);     // LDS atomic
        csr_src[start[bin] + 1 + r] = (int)(en & 0xffffu);
    }
}

// ---------------------------------------------------------------------------
// K2b (fused score + aggregate, wave-per-dst, depth-3 pipeline).
// ---------------------------------------------------------------------------
__global__ __launch_bounds__(256) void agg_fused(
    const int* __restrict__ csr_src, const int* __restrict__ offs,
    const bf16* __restrict__ xl, const bf16* __restrict__ xr,
    const float* __restrict__ att, const float* __restrict__ gb,
    bf16* __restrict__ h)
{
    int wid  = (blockIdx.x * 256 + threadIdx.x) >> 6;   // dst node
    int lane = threadIdx.x & 63;
    if (wid >= N_NODES) return;
    int g  = lane >> 3;   // edge slot within batch
    int c8 = lane & 7;    // channel octet

    float attv[8], xrv[8];
    {
        bf16x8 xrow = *(const bf16x8*)(xr + (size_t)wid * H_DIM + c8 * 8);
        float4 a0 = *(const float4*)(att + c8 * 8);
        float4 a1 = *(const float4*)(att + c8 * 8 + 4);
        attv[0] = a0.x; attv[1] = a0.y; attv[2] = a0.z; attv[3] = a0.w;
        attv[4] = a1.x; attv[5] = a1.y; attv[6] = a1.z; attv[7] = a1.w;
        #pragma unroll
        for (int j = 0; j < 8; ++j) xrv[j] = bs2f(xrow[j]);
    }

    int beg = offs[wid];
    int end = offs[wid + 1];          // >= beg+1 (self-loop)
    int last = end - 1;
    float den = 0.f;
    float acc[8] = {0.f, 0.f, 0.f, 0.f, 0.f, 0.f, 0.f, 0.f};

    int i0 = beg + g;        i0 = (i0 < end) ? i0 : last;
    int i1 = beg + 8 + g;    i1 = (i1 < end) ? i1 : last;
    int i2 = beg + 16 + g;   i2 = (i2 < end) ? i2 : last;
    int srcC = csr_src[i2];                                    // idx batch+2
    bf16x8 xa = *(const bf16x8*)(xl + (size_t)csr_src[i0] * H_DIM + c8 * 8);
    bf16x8 xb = *(const bf16x8*)(xl + (size_t)csr_src[i1] * H_DIM + c8 * 8);

    for (int base = beg; base < end; base += 8) {
        int i3 = base + 24 + g;  i3 = (i3 < end) ? i3 : last;
        int srcD = csr_src[i3];                                // idx batch+3
        bf16x8 xc = *(const bf16x8*)(xl + (size_t)srcC * H_DIM + c8 * 8);

        bool valid = (base + g) < end;
        float xv[8], p = 0.f;
        #pragma unroll
        for (int j = 0; j < 8; ++j) {
            xv[j] = bs2f(xa[j]);
            float m = xv[j] + xrv[j];
            m = (m > 0.f) ? m : 0.2f * m;
            p += m * attv[j];
        }
        p += __shfl_xor(p, 1);
        p += __shfl_xor(p, 2);
        p += __shfl_xor(p, 4);      // all lanes of group g now hold p_g
        float ex = valid ? __expf(p) : 0.f;
        den += ex;
        #pragma unroll
        for (int j = 0; j < 8; ++j) acc[j] += ex * xv[j];

        xa = xb;
        xb = xc;
        srcC = srcD;
    }

    // combine the 8 edge-groups (once per dst)
    #pragma unroll
    for (int j = 0; j < 8; ++j) {
        acc[j] += __shfl_xor(acc[j], 8);
        acc[j] += __shfl_xor(acc[j], 16);
        acc[j] += __shfl_xor(acc[j], 32);
    }
    den += __shfl_xor(den, 8);
    den += __shfl_xor(den, 16);
    den += __shfl_xor(den, 32);

    if (g == 0) {
        float inv = 1.0f / den;
        float4 g0 = *(const float4*)(gb + c8 * 8);
        float4 g1 = *(const float4*)(gb + c8 * 8 + 4);
        float gbv[8] = {g0.x, g0.y, g0.z, g0.w, g1.x, g1.y, g1.z, g1.w};
        bf16x8 ov;
        #pragma unroll
        for (int j = 0; j < 8; ++j) {
            float v = acc[j] * inv + gbv[j];
            v = (v > 0.f) ? v : expm1f(v);
            ov[j] = f2bs(v);
        }
        *(bf16x8*)(h + (size_t)wid * H_DIM + c8 * 8) = ov;
    }
}

// ---------------------------------------------------------------------------
// K3 (MFMA): logits = h @ Wo^T + bo (+ softplus(dispersion) tail on block 0).
// 32 nodes/block; B-frags from the prep pack; epilogue staged through a
// padded-row LDS tile (32 x 132 f32) -> per-wave-contiguous float4 stores.
// ---------------------------------------------------------------------------
__global__ __launch_bounds__(256) void out_mfma(
    const bf16* __restrict__ h,
    const bf16* __restrict__ wohi, const bf16* __restrict__ wolo,
    const float* __restrict__ bo, const float* __restrict__ disp,
    float* __restrict__ out)
{
    if (blockIdx.x == 0 && threadIdx.x < F_DIM) {
        float d = disp[threadIdx.x];
        out[(size_t)N_NODES * F_DIM + threadIdx.x] = (d > 20.f) ? d : log1pf(__expf(d));
    }

    __shared__ float ldso[32 * 132];   // +4 f32 row pad -> bank spread

    int wave = threadIdx.x >> 6;
    int lane = threadIdx.x & 63;
    int n = lane & 15, q = lane >> 4;
    int node0 = blockIdx.x * 32;

    bf16x8 bhi[2][2], blo_[2][2];
    float bov[2];
    #pragma unroll
    for (int nt = 0; nt < 2; ++nt) {
        int ch = wave * 32 + nt * 16 + n;
        #pragma unroll
        for (int ks = 0; ks < 2; ++ks) {
            int fid = wave * 4 + nt * 2 + ks;
            bhi[nt][ks]  = *(const bf16x8*)(wohi + ((size_t)fid * 64 + lane) * 8);
            blo_[nt][ks] = *(const bf16x8*)(wolo + ((size_t)fid * 64 + lane) * 8);
        }
        bov[nt] = bo[ch];
    }

    #pragma unroll
    for (int mt = 0; mt < 2; ++mt) {
        int nb = node0 + mt * 16;
        if (nb < N_NODES) {
            const bf16* hrow = h + (size_t)(nb + n) * H_DIM;
            bf16x8 a[2];
            #pragma unroll
            for (int ks = 0; ks < 2; ++ks)
                a[ks] = *(const bf16x8*)(hrow + ks * 32 + q * 8);
            f32x4 acc[2] = {{0.f,0.f,0.f,0.f},{0.f,0.f,0.f,0.f}};
            #pragma unroll
            for (int ks = 0; ks < 2; ++ks) {
                #pragma unroll
                for (int nt = 0; nt < 2; ++nt) {
                    acc[nt] = __builtin_amdgcn_mfma_f32_16x16x32_bf16(a[ks], bhi[nt][ks],  acc[nt], 0, 0, 0);
                    acc[nt] = __builtin_amdgcn_mfma_f32_16x16x32_bf16(a[ks], blo_[nt][ks], acc[nt], 0, 0, 0);
                }
            }
            #pragma unroll
            for (int nt = 0; nt < 2; ++nt) {
                int ch = wave * 32 + nt * 16 + n;
                #pragma unroll
                for (int r = 0; r < 4; ++r) {
                    int nodeL = mt * 16 + q * 4 + r;
                    ldso[nodeL * 132 + ch] = acc[nt][r] + bov[nt];
                }
            }
        }
    }
    __syncthreads();

    // Coalesced write-back: thread t -> node t>>3, 64B chunk t&7.
    int nl = threadIdx.x >> 3, c = threadIdx.x & 7;
    int node = node0 + nl;
    if (node < N_NODES) {
        const float* srcp = ldso + nl * 132 + c * 16;
        float* dstp = out + (size_t)node * F_DIM + c * 16;
        #pragma unroll
        for (int i = 0; i < 4; ++i)
            *(float4*)(dstp + i * 4) = *(const float4*)(srcp + i * 4);
    }
}

// ---------------------------------------------------------------------------
extern "C" void kernel_launch(void* const* d_in, const int* in_sizes, int n_in,
                              void* d_out, int out_size, void* d_ws, size_t ws_size,
                              hipStream_t stream)
{
    const float* xf  = (const float*)d_in[0];
    const float* xb  = (const float*)d_in[1];
    const int*   ei  = (const int*)d_in[2];    // [2, E] int32, row-major
    const float* Wl  = (const float*)d_in[3];
    const float* bl  = (const float*)d_in[4];
    const float* Wr  = (const float*)d_in[5];
    const float* br  = (const float*)d_in[6];
    const float* att = (const float*)d_in[7];
    const float* gb  = (const float*)d_in[8];
    const float* Wo  = (const float*)d_in[9];
    const float* bo  = (const float*)d_in[10];
    const float* dp  = (const float*)d_in[11];
    float* out = (float*)d_out;
    const int* esrc = ei;
    const int* edst = ei + N_EDGES;

    // ws layout (16B-aligned segments):
    //  xl bf16[N*64] | xr bf16[N*64] | h bf16[N*64] (bstore2 overlays h:
    //  written by h1's bucket half, read by csr, both before agg writes h) |
    //  csr_src int[ETOT] | offs int[N+4] | gtot int[208] | bofsT int[50176] |
    //  whi | wlo | wohi | wolo
    char* ws = (char*)d_ws;
    const size_t SZB = (size_t)N_NODES * H_DIM * sizeof(bf16);   // 6.4 MB
    bf16*  xl      = (bf16*)(ws);
    bf16*  xr      = (bf16*)(ws + SZB);
    bf16*  h       = (bf16*)(ws + 2 * SZB);
    unsigned* bstore2 = (unsigned*)h;         // overlay (3.2 MB <= 6.4 MB)
    int*   csr_src = (int*)(ws + 3 * SZB);
    int*   offs    = (int*)(ws + 3 * SZB + (size_t)ETOT * 4);
    int*   gtot    = offs + (N_NODES + 4);
    int*   bofsT   = gtot + 208;              // [196][256] packed (base<<16|cnt)
    bf16*  whi     = (bf16*)(bofsT + NB * 256);
    bf16*  wlo     = whi + 16384;
    bf16*  wohi    = wlo + 16384;
    bf16*  wolo    = wohi + 8192;

    prep_kernel<<<13, 256, 0, stream>>>(Wl, Wr, Wo, whi, wlo, wohi, wolo, gtot);

    h1_kernel<<<PROJ_BLKS + BKT_BLKS, 256, 0, stream>>>(
        xf, xb, Wl, bl, Wr, br, whi, wlo, esrc, edst, xl, xr,
        gtot, bstore2, bofsT);

    csr_kernel<<<NB, 512, 0, stream>>>(gtot, bstore2, bofsT, offs, csr_src);

    agg_fused<<<(N_NODES * 64) / 256, 256, 0, stream>>>(csr_src, offs,
                                                        xl, xr, att, gb, h);

    out_mfma<<<OUT_BLKS, 256, 0, stream>>>(h, wohi, wolo, bo, dp, out);
}